// Round 1
// baseline (585.891 us; speedup 1.0000x reference)
//
#include <hip/hip_runtime.h>

typedef __attribute__((ext_vector_type(8))) short bf16x8;
typedef __attribute__((ext_vector_type(4))) float f32x4;

__device__ __forceinline__ ushort f2bf(float f) {
  union { float f; unsigned u; } v; v.f = f;
  unsigned r = v.u + 0x7fffu + ((v.u >> 16) & 1u);
  return (ushort)(r >> 16);
}

__device__ __forceinline__ void gload_lds16(const void* g, void* l) {
  __builtin_amdgcn_global_load_lds(
      (const __attribute__((address_space(1))) void*)g,
      (__attribute__((address_space(3))) void*)l, 16, 0, 0);
}

// ---------------- conversion kernels ----------------

__global__ void cvt_f32_bf16(const float* __restrict__ s, ushort* __restrict__ d, int n) {
  int i = (blockIdx.x * blockDim.x + threadIdx.x) * 4;
  int stride = gridDim.x * blockDim.x * 4;
  for (; i < n; i += stride) {
    float4 v = *reinterpret_cast<const float4*>(s + i);
    ushort4 o;
    o.x = f2bf(v.x); o.y = f2bf(v.y); o.z = f2bf(v.z); o.w = f2bf(v.w);
    *reinterpret_cast<ushort4*>(d + i) = o;
  }
}

// src [R][C] f32 -> dst [C][R] bf16
__global__ void transpose_cvt(const float* __restrict__ src, ushort* __restrict__ dst,
                              int R, int C) {
  __shared__ float tile[32][33];
  int c0 = blockIdx.x * 32, r0 = blockIdx.y * 32;
  int tx = threadIdx.x, ty = threadIdx.y;  // 32 x 8
  #pragma unroll
  for (int i = 0; i < 32; i += 8)
    tile[ty + i][tx] = src[(size_t)(r0 + ty + i) * C + c0 + tx];
  __syncthreads();
  #pragma unroll
  for (int i = 0; i < 32; i += 8)
    dst[(size_t)(c0 + ty + i) * R + r0 + tx] = f2bf(tile[tx][ty + i]);
}

// ---------------- GEMM1: qkv = x @ w_qkv + b, scatter to q/k/vT ----------------
// A [8192][1024] bf16, Bt [3072][1024] bf16 (w_qkv transposed)
// q,k: [64 bh][2048 n][64 d]  vT: [64 bh][64 d][2048 n]

__global__ void gemm_qkv(const ushort* __restrict__ A, const ushort* __restrict__ Bt,
                         const float* __restrict__ bias,
                         ushort* __restrict__ q, ushort* __restrict__ k,
                         ushort* __restrict__ vT) {
  constexpr int K = 1024;
  __shared__ __align__(16) ushort sA[128 * 32];
  __shared__ __align__(16) ushort sB[128 * 32];
  const int tid = threadIdx.x;
  const int lane = tid & 63;
  const int w = tid >> 6;
  const int wr = w >> 1, wc = w & 1;
  const int bm = blockIdx.y * 128;
  const int bn = blockIdx.x * 128;
  f32x4 acc[4][4] = {};
  const int srow = lane >> 2;       // 0..15 within 16-row chunk
  const int skb = (lane & 3) * 8;   // bf16-element offset within 32

  for (int kt = 0; kt < K; kt += 32) {
    #pragma unroll
    for (int i = 0; i < 2; ++i) {
      const int chunk = w * 2 + i;
      const int row = chunk * 16 + srow;
      gload_lds16(A + (size_t)(bm + row) * K + kt + skb, sA + chunk * 512);
      gload_lds16(Bt + (size_t)(bn + row) * K + kt + skb, sB + chunk * 512);
    }
    __syncthreads();
    bf16x8 af[4], bfr[4];
    #pragma unroll
    for (int mi = 0; mi < 4; ++mi)
      af[mi] = *(const bf16x8*)(sA + (wr * 64 + mi * 16 + (lane & 15)) * 32 + (lane >> 4) * 8);
    #pragma unroll
    for (int ni = 0; ni < 4; ++ni)
      bfr[ni] = *(const bf16x8*)(sB + (wc * 64 + ni * 16 + (lane & 15)) * 32 + (lane >> 4) * 8);
    #pragma unroll
    for (int mi = 0; mi < 4; ++mi)
      #pragma unroll
      for (int ni = 0; ni < 4; ++ni)
        acc[mi][ni] = __builtin_amdgcn_mfma_f32_16x16x32_bf16(af[mi], bfr[ni], acc[mi][ni], 0, 0, 0);
    __syncthreads();
  }

  #pragma unroll
  for (int mi = 0; mi < 4; ++mi)
    #pragma unroll
    for (int ni = 0; ni < 4; ++ni) {
      const int col = bn + wc * 64 + ni * 16 + (lane & 15);
      const int t = col >> 10;          // 0:q 1:k 2:v
      const int h = (col >> 6) & 15;
      const int d = col & 63;
      const float bb = bias[col];
      #pragma unroll
      for (int r = 0; r < 4; ++r) {
        const int row = bm + wr * 64 + mi * 16 + (lane >> 4) * 4 + r;
        const int b_ = row >> 11, n = row & 2047;
        const int bh = b_ * 16 + h;
        const ushort hv = f2bf(acc[mi][ni][r] + bb);
        if (t == 0)      q[((size_t)bh * 2048 + n) * 64 + d] = hv;
        else if (t == 1) k[((size_t)bh * 2048 + n) * 64 + d] = hv;
        else             vT[((size_t)bh * 64 + d) * 2048 + n] = hv;
      }
    }
}

// ---------------- flash attention ----------------
// grid (32 qtiles, 64 bh), block 256 (4 waves); wave owns 16 q-rows.

__global__ void attn_fwd(const ushort* __restrict__ q, const ushort* __restrict__ k,
                         const ushort* __restrict__ vT, ushort* __restrict__ o) {
  __shared__ __align__(16) ushort pbuf[4][16 * 64];
  const int tid = threadIdx.x, lane = tid & 63, w = tid >> 6;
  const int bh = blockIdx.y;
  const int qrow0 = blockIdx.x * 64 + w * 16;
  const ushort* Qb = q + (size_t)bh * 2048 * 64;
  const ushort* Kb = k + (size_t)bh * 2048 * 64;
  const ushort* Vb = vT + (size_t)bh * 64 * 2048;
  const int lr = lane & 15, lg = lane >> 4;

  bf16x8 qf[2];
  #pragma unroll
  for (int ks = 0; ks < 2; ++ks)
    qf[ks] = *(const bf16x8*)(Qb + (size_t)(qrow0 + lr) * 64 + ks * 32 + lg * 8);

  float mrow[4], lrow[4];
  f32x4 oacc[4] = {};
  #pragma unroll
  for (int r = 0; r < 4; ++r) { mrow[r] = -1e30f; lrow[r] = 0.f; }

  ushort* pb = &pbuf[w][0];
  const float sc = 0.125f;  // 64^-0.5

  for (int kv = 0; kv < 2048; kv += 64) {
    f32x4 s[4] = {};
    #pragma unroll
    for (int nt = 0; nt < 4; ++nt)
      #pragma unroll
      for (int ks = 0; ks < 2; ++ks) {
        bf16x8 kf = *(const bf16x8*)(Kb + (size_t)(kv + nt * 16 + lr) * 64 + ks * 32 + lg * 8);
        s[nt] = __builtin_amdgcn_mfma_f32_16x16x32_bf16(qf[ks], kf, s[nt], 0, 0, 0);
      }
    // online softmax: rows (lg*4+r), cols across lr and nt
    float corr[4], rsum[4];
    #pragma unroll
    for (int r = 0; r < 4; ++r) {
      float mx = fmaxf(fmaxf(s[0][r], s[1][r]), fmaxf(s[2][r], s[3][r]));
      #pragma unroll
      for (int off = 1; off < 16; off <<= 1) mx = fmaxf(mx, __shfl_xor(mx, off, 64));
      mx *= sc;
      const float mnew = fmaxf(mrow[r], mx);
      corr[r] = __expf(mrow[r] - mnew);
      mrow[r] = mnew;
      rsum[r] = 0.f;
    }
    #pragma unroll
    for (int nt = 0; nt < 4; ++nt)
      #pragma unroll
      for (int r = 0; r < 4; ++r) {
        const float pv = __expf(s[nt][r] * sc - mrow[r]);
        rsum[r] += pv;
        pb[(lg * 4 + r) * 64 + nt * 16 + lr] = f2bf(pv);
      }
    #pragma unroll
    for (int r = 0; r < 4; ++r) {
      float t = rsum[r];
      #pragma unroll
      for (int off = 1; off < 16; off <<= 1) t += __shfl_xor(t, off, 64);
      lrow[r] = lrow[r] * corr[r] + t;
    }
    #pragma unroll
    for (int dt = 0; dt < 4; ++dt)
      #pragma unroll
      for (int r = 0; r < 4; ++r) oacc[dt][r] *= corr[r];
    // PV: A = P (from LDS), B = V^T rows
    bf16x8 pa[2];
    #pragma unroll
    for (int ks = 0; ks < 2; ++ks)
      pa[ks] = *(const bf16x8*)(pb + lr * 64 + ks * 32 + lg * 8);
    #pragma unroll
    for (int dt = 0; dt < 4; ++dt)
      #pragma unroll
      for (int ks = 0; ks < 2; ++ks) {
        bf16x8 vf = *(const bf16x8*)(Vb + (size_t)(dt * 16 + lr) * 2048 + kv + ks * 32 + lg * 8);
        oacc[dt] = __builtin_amdgcn_mfma_f32_16x16x32_bf16(pa[ks], vf, oacc[dt], 0, 0, 0);
      }
  }

  const int b_ = bh >> 4, h = bh & 15;
  #pragma unroll
  for (int dt = 0; dt < 4; ++dt)
    #pragma unroll
    for (int r = 0; r < 4; ++r) {
      const int n = qrow0 + lg * 4 + r;
      o[(((size_t)b_ * 2048 + n) * 16 + h) * 64 + dt * 16 + lr] = f2bf(oacc[dt][r] / lrow[r]);
    }
}

// ---------------- GEMM2: out = attn @ w_out + b_out (f32 out) ----------------

__global__ void gemm_out(const ushort* __restrict__ A, const ushort* __restrict__ Bt,
                         const float* __restrict__ bias, float* __restrict__ out) {
  constexpr int K = 1024;
  __shared__ __align__(16) ushort sA[128 * 32];
  __shared__ __align__(16) ushort sB[128 * 32];
  const int tid = threadIdx.x;
  const int lane = tid & 63;
  const int w = tid >> 6;
  const int wr = w >> 1, wc = w & 1;
  const int bm = blockIdx.y * 128;
  const int bn = blockIdx.x * 128;
  f32x4 acc[4][4] = {};
  const int srow = lane >> 2;
  const int skb = (lane & 3) * 8;

  for (int kt = 0; kt < K; kt += 32) {
    #pragma unroll
    for (int i = 0; i < 2; ++i) {
      const int chunk = w * 2 + i;
      const int row = chunk * 16 + srow;
      gload_lds16(A + (size_t)(bm + row) * K + kt + skb, sA + chunk * 512);
      gload_lds16(Bt + (size_t)(bn + row) * K + kt + skb, sB + chunk * 512);
    }
    __syncthreads();
    bf16x8 af[4], bfr[4];
    #pragma unroll
    for (int mi = 0; mi < 4; ++mi)
      af[mi] = *(const bf16x8*)(sA + (wr * 64 + mi * 16 + (lane & 15)) * 32 + (lane >> 4) * 8);
    #pragma unroll
    for (int ni = 0; ni < 4; ++ni)
      bfr[ni] = *(const bf16x8*)(sB + (wc * 64 + ni * 16 + (lane & 15)) * 32 + (lane >> 4) * 8);
    #pragma unroll
    for (int mi = 0; mi < 4; ++mi)
      #pragma unroll
      for (int ni = 0; ni < 4; ++ni)
        acc[mi][ni] = __builtin_amdgcn_mfma_f32_16x16x32_bf16(af[mi], bfr[ni], acc[mi][ni], 0, 0, 0);
    __syncthreads();
  }

  #pragma unroll
  for (int mi = 0; mi < 4; ++mi)
    #pragma unroll
    for (int ni = 0; ni < 4; ++ni) {
      const int col = bn + wc * 64 + ni * 16 + (lane & 15);
      const float bb = bias[col];
      #pragma unroll
      for (int r = 0; r < 4; ++r) {
        const int row = bm + wr * 64 + mi * 16 + (lane >> 4) * 4 + r;
        out[(size_t)row * 1024 + col] = acc[mi][ni][r] + bb;
      }
    }
}

// ---------------- launch ----------------

extern "C" void kernel_launch(void* const* d_in, const int* in_sizes, int n_in,
                              void* d_out, int out_size, void* d_ws, size_t ws_size,
                              hipStream_t stream) {
  const float* x = (const float*)d_in[0];
  const float* w_qkv = (const float*)d_in[1];
  const float* b_qkv = (const float*)d_in[2];
  const float* w_out = (const float*)d_in[3];
  const float* b_out = (const float*)d_in[4];
  float* out = (float*)d_out;
  char* ws = (char*)d_ws;

  ushort* xb    = (ushort*)(ws);                 // 8192*1024*2 = 16 MiB
  ushort* wqkvT = (ushort*)(ws + 16777216);      // 3072*1024*2 = 6 MiB
  ushort* woutT = (ushort*)(ws + 23068672);      // 1024*1024*2 = 2 MiB
  ushort* qb    = (ushort*)(ws + 25165824);      // 16 MiB
  ushort* kb    = (ushort*)(ws + 41943040);      // 16 MiB
  ushort* vTb   = (ushort*)(ws + 58720256);      // 16 MiB
  ushort* attnb = (ushort*)(ws + 75497472);      // 16 MiB (ends at 92274688)

  cvt_f32_bf16<<<2048, 256, 0, stream>>>(x, xb, 8192 * 1024);
  transpose_cvt<<<dim3(96, 32), dim3(32, 8), 0, stream>>>(w_qkv, wqkvT, 1024, 3072);
  transpose_cvt<<<dim3(32, 32), dim3(32, 8), 0, stream>>>(w_out, woutT, 1024, 1024);
  gemm_qkv<<<dim3(24, 64), 256, 0, stream>>>(xb, wqkvT, b_qkv, qb, kb, vTb);
  attn_fwd<<<dim3(32, 64), 256, 0, stream>>>(qb, kb, vTb, attnb);
  gemm_out<<<dim3(8, 64), 256, 0, stream>>>(attnb, woutT, b_out, out);
}

// Round 2
// 581.603 us; speedup vs baseline: 1.0074x; 1.0074x over previous
//
#include <hip/hip_runtime.h>

typedef __attribute__((ext_vector_type(8))) short bf16x8;
typedef __attribute__((ext_vector_type(4))) float f32x4;
typedef __attribute__((ext_vector_type(4))) ushort u16x4;

__device__ __forceinline__ ushort f2bf(float f) {
  union { float f; unsigned u; } v; v.f = f;
  unsigned r = v.u + 0x7fffu + ((v.u >> 16) & 1u);
  return (ushort)(r >> 16);
}

__device__ __forceinline__ float bf2f(ushort u) {
  union { float f; unsigned u; } v; v.u = (unsigned)u << 16;
  return v.f;
}

__device__ __forceinline__ void gload_lds16(const void* g, void* l) {
  __builtin_amdgcn_global_load_lds(
      (const __attribute__((address_space(1))) void*)g,
      (__attribute__((address_space(3))) void*)l, 16, 0, 0);
}

// ---------------- conversion kernels ----------------

__global__ void cvt_f32_bf16(const float* __restrict__ s, ushort* __restrict__ d, int n) {
  int i = (blockIdx.x * blockDim.x + threadIdx.x) * 4;
  int stride = gridDim.x * blockDim.x * 4;
  for (; i < n; i += stride) {
    float4 v = *reinterpret_cast<const float4*>(s + i);
    ushort4 o;
    o.x = f2bf(v.x); o.y = f2bf(v.y); o.z = f2bf(v.z); o.w = f2bf(v.w);
    *reinterpret_cast<ushort4*>(d + i) = o;
  }
}

// src [R][C] f32 -> dst [C][R] bf16
__global__ void transpose_cvt(const float* __restrict__ src, ushort* __restrict__ dst,
                              int R, int C) {
  __shared__ float tile[32][33];
  int c0 = blockIdx.x * 32, r0 = blockIdx.y * 32;
  int tx = threadIdx.x, ty = threadIdx.y;  // 32 x 8
  #pragma unroll
  for (int i = 0; i < 32; i += 8)
    tile[ty + i][tx] = src[(size_t)(r0 + ty + i) * C + c0 + tx];
  __syncthreads();
  #pragma unroll
  for (int i = 0; i < 32; i += 8)
    dst[(size_t)(c0 + ty + i) * R + r0 + tx] = f2bf(tile[tx][ty + i]);
}

// ---------------- GEMM1: qkv = x @ w_qkv + b, scatter to q/k/vT ----------------

__global__ void gemm_qkv(const ushort* __restrict__ A, const ushort* __restrict__ Bt,
                         const float* __restrict__ bias,
                         ushort* __restrict__ q, ushort* __restrict__ k,
                         ushort* __restrict__ vT) {
  constexpr int K = 1024;
  __shared__ __align__(16) ushort sA[128 * 32];
  __shared__ __align__(16) ushort sB[128 * 32];
  const int tid = threadIdx.x;
  const int lane = tid & 63;
  const int w = tid >> 6;
  const int wr = w >> 1, wc = w & 1;
  const int bm = blockIdx.y * 128;
  const int bn = blockIdx.x * 128;
  f32x4 acc[4][4] = {};
  const int srow = lane >> 2;
  const int skb = (lane & 3) * 8;

  for (int kt = 0; kt < K; kt += 32) {
    #pragma unroll
    for (int i = 0; i < 2; ++i) {
      const int chunk = w * 2 + i;
      const int row = chunk * 16 + srow;
      gload_lds16(A + (size_t)(bm + row) * K + kt + skb, sA + chunk * 512);
      gload_lds16(Bt + (size_t)(bn + row) * K + kt + skb, sB + chunk * 512);
    }
    __syncthreads();
    bf16x8 af[4], bfr[4];
    #pragma unroll
    for (int mi = 0; mi < 4; ++mi)
      af[mi] = *(const bf16x8*)(sA + (wr * 64 + mi * 16 + (lane & 15)) * 32 + (lane >> 4) * 8);
    #pragma unroll
    for (int ni = 0; ni < 4; ++ni)
      bfr[ni] = *(const bf16x8*)(sB + (wc * 64 + ni * 16 + (lane & 15)) * 32 + (lane >> 4) * 8);
    #pragma unroll
    for (int mi = 0; mi < 4; ++mi)
      #pragma unroll
      for (int ni = 0; ni < 4; ++ni)
        acc[mi][ni] = __builtin_amdgcn_mfma_f32_16x16x32_bf16(af[mi], bfr[ni], acc[mi][ni], 0, 0, 0);
    __syncthreads();
  }

  #pragma unroll
  for (int mi = 0; mi < 4; ++mi)
    #pragma unroll
    for (int ni = 0; ni < 4; ++ni) {
      const int col = bn + wc * 64 + ni * 16 + (lane & 15);
      const int t = col >> 10;
      const int h = (col >> 6) & 15;
      const int d = col & 63;
      const float bb = bias[col];
      #pragma unroll
      for (int r = 0; r < 4; ++r) {
        const int row = bm + wr * 64 + mi * 16 + (lane >> 4) * 4 + r;
        const int b_ = row >> 11, n = row & 2047;
        const int bh = b_ * 16 + h;
        const ushort hv = f2bf(acc[mi][ni][r] + bb);
        if (t == 0)      q[((size_t)bh * 2048 + n) * 64 + d] = hv;
        else if (t == 1) k[((size_t)bh * 2048 + n) * 64 + d] = hv;
        else             vT[((size_t)bh * 64 + d) * 2048 + n] = hv;
      }
    }
}

// ---------------- flash attention (swapped QK^T, in-lane softmax) ----------------
// grid (32 qtiles, 64 bh), block 256 (4 waves); wave owns 16 q-rows.
// S^T = mfma(K_frag, Q_frag): lane holds S[q = lane&15][kv = nt*16 + lg*4 + r].

__global__ void attn_fwd(const ushort* __restrict__ q, const ushort* __restrict__ k,
                         const ushort* __restrict__ vT, ushort* __restrict__ o) {
  __shared__ __align__(16) ushort pbuf[4][16 * 64];
  const int tid = threadIdx.x, lane = tid & 63, w = tid >> 6;
  const int bh = blockIdx.y;
  const int qrow0 = blockIdx.x * 64 + w * 16;
  const ushort* Qb = q + (size_t)bh * 2048 * 64;
  const ushort* Kb = k + (size_t)bh * 2048 * 64;
  const ushort* Vb = vT + (size_t)bh * 64 * 2048;
  const int lr = lane & 15, lg = lane >> 4;
  char* pb = (char*)&pbuf[w][0];
  const int swz = (lr & 7) << 4;

  // Q fragment, pre-scaled by 1/sqrt(64) = 0.125 (exact pow2: no rounding)
  bf16x8 qf[2];
  #pragma unroll
  for (int ks = 0; ks < 2; ++ks) {
    bf16x8 t = *(const bf16x8*)(Qb + (size_t)(qrow0 + lr) * 64 + ks * 32 + lg * 8);
    #pragma unroll
    for (int j = 0; j < 8; ++j)
      t[j] = (short)f2bf(bf2f((ushort)t[j]) * 0.125f);
    qf[ks] = t;
  }

  float m_run = -1e30f, l_run = 0.f;
  f32x4 oacc[4] = {};

  for (int kv = 0; kv < 2048; kv += 64) {
    // K fragments (A-operand of swapped QK^T)
    bf16x8 kf[4][2];
    #pragma unroll
    for (int nt = 0; nt < 4; ++nt)
      #pragma unroll
      for (int ks = 0; ks < 2; ++ks)
        kf[nt][ks] = *(const bf16x8*)(Kb + (size_t)(kv + nt * 16 + lr) * 64 + ks * 32 + lg * 8);
    f32x4 s[4] = {};
    #pragma unroll
    for (int nt = 0; nt < 4; ++nt)
      #pragma unroll
      for (int ks = 0; ks < 2; ++ks)
        s[nt] = __builtin_amdgcn_mfma_f32_16x16x32_bf16(kf[nt][ks], qf[ks], s[nt], 0, 0, 0);

    // V fragments issued early: latency hides under softmax VALU work
    bf16x8 vf[4][2];
    #pragma unroll
    for (int dt = 0; dt < 4; ++dt)
      #pragma unroll
      for (int ks = 0; ks < 2; ++ks)
        vf[dt][ks] = *(const bf16x8*)(Vb + (size_t)(dt * 16 + lr) * 2048 + kv + ks * 32 + lg * 8);

    // in-lane partial max over this lane's 16 S values (all same q-row)
    float pmax = s[0][0];
    #pragma unroll
    for (int nt = 0; nt < 4; ++nt)
      #pragma unroll
      for (int r = 0; r < 4; ++r) pmax = fmaxf(pmax, s[nt][r]);

    // defer-max (T13): only rescale when some row grew by > 8
    if (!__all(pmax <= m_run + 8.f)) {
      float rm = fmaxf(pmax, __shfl_xor(pmax, 16, 64));
      rm = fmaxf(rm, __shfl_xor(rm, 32, 64));
      const float mnew = fmaxf(m_run, rm);
      const float corr = __expf(m_run - mnew);  // valid for q = lr
      m_run = mnew;
      l_run *= corr;
      #pragma unroll
      for (int r = 0; r < 4; ++r) {
        const float c = __shfl(corr, lg * 4 + r, 64);  // corr for q = lg*4+r
        #pragma unroll
        for (int dt = 0; dt < 4; ++dt) oacc[dt][r] *= c;
      }
    }

    // exp, row-sum, pack P to swizzled LDS (2-way max bank aliasing = free)
    float psum = 0.f;
    #pragma unroll
    for (int nt = 0; nt < 4; ++nt) {
      u16x4 u;
      #pragma unroll
      for (int r = 0; r < 4; ++r) {
        const float e = __expf(s[nt][r] - m_run);
        psum += e;
        u[r] = f2bf(e);
      }
      *(u16x4*)(pb + lr * 128 + ((nt * 32 + lg * 8) ^ swz)) = u;
    }
    psum += __shfl_xor(psum, 16, 64);
    psum += __shfl_xor(psum, 32, 64);
    l_run += psum;

    // PV: A = P rows (q-major), B^T = V^T rows (d-major)
    bf16x8 pa[2];
    #pragma unroll
    for (int ks = 0; ks < 2; ++ks)
      pa[ks] = *(const bf16x8*)(pb + lr * 128 + ((ks * 64 + lg * 16) ^ swz));
    #pragma unroll
    for (int dt = 0; dt < 4; ++dt)
      #pragma unroll
      for (int ks = 0; ks < 2; ++ks)
        oacc[dt] = __builtin_amdgcn_mfma_f32_16x16x32_bf16(pa[ks], vf[dt][ks], oacc[dt], 0, 0, 0);
  }

  // epilogue: O row = q = lg*4+r, col = dt*16+lr; fetch l for that row
  const int b_ = bh >> 4, h = bh & 15;
  float lf[4];
  #pragma unroll
  for (int r = 0; r < 4; ++r) lf[r] = __shfl(l_run, lg * 4 + r, 64);
  #pragma unroll
  for (int dt = 0; dt < 4; ++dt)
    #pragma unroll
    for (int r = 0; r < 4; ++r) {
      const int n = qrow0 + lg * 4 + r;
      o[(((size_t)b_ * 2048 + n) * 16 + h) * 64 + dt * 16 + lr] = f2bf(oacc[dt][r] / lf[r]);
    }
}

// ---------------- GEMM2: out = attn @ w_out + b_out (f32 out) ----------------

__global__ void gemm_out(const ushort* __restrict__ A, const ushort* __restrict__ Bt,
                         const float* __restrict__ bias, float* __restrict__ out) {
  constexpr int K = 1024;
  __shared__ __align__(16) ushort sA[128 * 32];
  __shared__ __align__(16) ushort sB[128 * 32];
  const int tid = threadIdx.x;
  const int lane = tid & 63;
  const int w = tid >> 6;
  const int wr = w >> 1, wc = w & 1;
  const int bm = blockIdx.y * 128;
  const int bn = blockIdx.x * 128;
  f32x4 acc[4][4] = {};
  const int srow = lane >> 2;
  const int skb = (lane & 3) * 8;

  for (int kt = 0; kt < K; kt += 32) {
    #pragma unroll
    for (int i = 0; i < 2; ++i) {
      const int chunk = w * 2 + i;
      const int row = chunk * 16 + srow;
      gload_lds16(A + (size_t)(bm + row) * K + kt + skb, sA + chunk * 512);
      gload_lds16(Bt + (size_t)(bn + row) * K + kt + skb, sB + chunk * 512);
    }
    __syncthreads();
    bf16x8 af[4], bfr[4];
    #pragma unroll
    for (int mi = 0; mi < 4; ++mi)
      af[mi] = *(const bf16x8*)(sA + (wr * 64 + mi * 16 + (lane & 15)) * 32 + (lane >> 4) * 8);
    #pragma unroll
    for (int ni = 0; ni < 4; ++ni)
      bfr[ni] = *(const bf16x8*)(sB + (wc * 64 + ni * 16 + (lane & 15)) * 32 + (lane >> 4) * 8);
    #pragma unroll
    for (int mi = 0; mi < 4; ++mi)
      #pragma unroll
      for (int ni = 0; ni < 4; ++ni)
        acc[mi][ni] = __builtin_amdgcn_mfma_f32_16x16x32_bf16(af[mi], bfr[ni], acc[mi][ni], 0, 0, 0);
    __syncthreads();
  }

  #pragma unroll
  for (int mi = 0; mi < 4; ++mi)
    #pragma unroll
    for (int ni = 0; ni < 4; ++ni) {
      const int col = bn + wc * 64 + ni * 16 + (lane & 15);
      const float bb = bias[col];
      #pragma unroll
      for (int r = 0; r < 4; ++r) {
        const int row = bm + wr * 64 + mi * 16 + (lane >> 4) * 4 + r;
        out[(size_t)row * 1024 + col] = acc[mi][ni][r] + bb;
      }
    }
}

// ---------------- launch ----------------

extern "C" void kernel_launch(void* const* d_in, const int* in_sizes, int n_in,
                              void* d_out, int out_size, void* d_ws, size_t ws_size,
                              hipStream_t stream) {
  const float* x = (const float*)d_in[0];
  const float* w_qkv = (const float*)d_in[1];
  const float* b_qkv = (const float*)d_in[2];
  const float* w_out = (const float*)d_in[3];
  const float* b_out = (const float*)d_in[4];
  float* out = (float*)d_out;
  char* ws = (char*)d_ws;

  ushort* xb    = (ushort*)(ws);                 // 16 MiB
  ushort* wqkvT = (ushort*)(ws + 16777216);      // 6 MiB
  ushort* woutT = (ushort*)(ws + 23068672);      // 2 MiB
  ushort* qb    = (ushort*)(ws + 25165824);      // 16 MiB
  ushort* kb    = (ushort*)(ws + 41943040);      // 16 MiB
  ushort* vTb   = (ushort*)(ws + 58720256);      // 16 MiB
  ushort* attnb = (ushort*)(ws + 75497472);      // 16 MiB

  cvt_f32_bf16<<<2048, 256, 0, stream>>>(x, xb, 8192 * 1024);
  transpose_cvt<<<dim3(96, 32), dim3(32, 8), 0, stream>>>(w_qkv, wqkvT, 1024, 3072);
  transpose_cvt<<<dim3(32, 32), dim3(32, 8), 0, stream>>>(w_out, woutT, 1024, 1024);
  gemm_qkv<<<dim3(24, 64), 256, 0, stream>>>(xb, wqkvT, b_qkv, qb, kb, vTb);
  attn_fwd<<<dim3(32, 64), 256, 0, stream>>>(qb, kb, vTb, attnb);
  gemm_out<<<dim3(8, 64), 256, 0, stream>>>(attnb, woutT, b_out, out);
}

// Round 3
// 249.300 us; speedup vs baseline: 2.3501x; 2.3329x over previous
//
#include <hip/hip_runtime.h>

typedef __attribute__((ext_vector_type(8))) short bf16x8;
typedef __attribute__((ext_vector_type(4))) float f32x4;
typedef __attribute__((ext_vector_type(4))) ushort u16x4;

__device__ __forceinline__ ushort f2bf(float f) {
  union { float f; unsigned u; } v; v.f = f;
  unsigned r = v.u + 0x7fffu + ((v.u >> 16) & 1u);
  return (ushort)(r >> 16);
}

__device__ __forceinline__ float bf2f(ushort u) {
  union { float f; unsigned u; } v; v.u = (unsigned)u << 16;
  return v.f;
}

__device__ __forceinline__ void gload_lds16(const void* g, void* l) {
  __builtin_amdgcn_global_load_lds(
      (const __attribute__((address_space(1))) void*)g,
      (__attribute__((address_space(3))) void*)l, 16, 0, 0);
}

// ---------------- conversion kernels ----------------

__global__ void cvt_f32_bf16(const float* __restrict__ s, ushort* __restrict__ d, int n) {
  int i = (blockIdx.x * blockDim.x + threadIdx.x) * 4;
  int stride = gridDim.x * blockDim.x * 4;
  for (; i < n; i += stride) {
    float4 v = *reinterpret_cast<const float4*>(s + i);
    ushort4 o;
    o.x = f2bf(v.x); o.y = f2bf(v.y); o.z = f2bf(v.z); o.w = f2bf(v.w);
    *reinterpret_cast<ushort4*>(d + i) = o;
  }
}

// src [R][C] f32 -> dst [C][R] bf16
__global__ void transpose_cvt(const float* __restrict__ src, ushort* __restrict__ dst,
                              int R, int C) {
  __shared__ float tile[32][33];
  int c0 = blockIdx.x * 32, r0 = blockIdx.y * 32;
  int tx = threadIdx.x, ty = threadIdx.y;  // 32 x 8
  #pragma unroll
  for (int i = 0; i < 32; i += 8)
    tile[ty + i][tx] = src[(size_t)(r0 + ty + i) * C + c0 + tx];
  __syncthreads();
  #pragma unroll
  for (int i = 0; i < 32; i += 8)
    dst[(size_t)(c0 + ty + i) * R + r0 + tx] = f2bf(tile[tx][ty + i]);
}

// ---------------- GEMM1: qkv = x @ w_qkv + b, scatter to q/k/vT ----------------

__global__ void gemm_qkv(const ushort* __restrict__ A, const ushort* __restrict__ Bt,
                         const float* __restrict__ bias,
                         ushort* __restrict__ q, ushort* __restrict__ k,
                         ushort* __restrict__ vT) {
  constexpr int K = 1024;
  __shared__ __align__(16) ushort sA[128 * 32];
  __shared__ __align__(16) ushort sB[128 * 32];
  const int tid = threadIdx.x;
  const int lane = tid & 63;
  const int w = tid >> 6;
  const int wr = w >> 1, wc = w & 1;
  const int bm = blockIdx.y * 128;
  const int bn = blockIdx.x * 128;
  f32x4 acc[4][4] = {};
  const int srow = lane >> 2;
  const int skb = (lane & 3) * 8;

  for (int kt = 0; kt < K; kt += 32) {
    #pragma unroll
    for (int i = 0; i < 2; ++i) {
      const int chunk = w * 2 + i;
      const int row = chunk * 16 + srow;
      gload_lds16(A + (size_t)(bm + row) * K + kt + skb, sA + chunk * 512);
      gload_lds16(Bt + (size_t)(bn + row) * K + kt + skb, sB + chunk * 512);
    }
    __syncthreads();
    bf16x8 af[4], bfr[4];
    #pragma unroll
    for (int mi = 0; mi < 4; ++mi)
      af[mi] = *(const bf16x8*)(sA + (wr * 64 + mi * 16 + (lane & 15)) * 32 + (lane >> 4) * 8);
    #pragma unroll
    for (int ni = 0; ni < 4; ++ni)
      bfr[ni] = *(const bf16x8*)(sB + (wc * 64 + ni * 16 + (lane & 15)) * 32 + (lane >> 4) * 8);
    #pragma unroll
    for (int mi = 0; mi < 4; ++mi)
      #pragma unroll
      for (int ni = 0; ni < 4; ++ni)
        acc[mi][ni] = __builtin_amdgcn_mfma_f32_16x16x32_bf16(af[mi], bfr[ni], acc[mi][ni], 0, 0, 0);
    __syncthreads();
  }

  #pragma unroll
  for (int mi = 0; mi < 4; ++mi)
    #pragma unroll
    for (int ni = 0; ni < 4; ++ni) {
      const int col = bn + wc * 64 + ni * 16 + (lane & 15);
      const int t = col >> 10;
      const int h = (col >> 6) & 15;
      const int d = col & 63;
      const float bb = bias[col];
      #pragma unroll
      for (int r = 0; r < 4; ++r) {
        const int row = bm + wr * 64 + mi * 16 + (lane >> 4) * 4 + r;
        const int b_ = row >> 11, n = row & 2047;
        const int bh = b_ * 16 + h;
        const ushort hv = f2bf(acc[mi][ni][r] + bb);
        if (t == 0)      q[((size_t)bh * 2048 + n) * 64 + d] = hv;
        else if (t == 1) k[((size_t)bh * 2048 + n) * 64 + d] = hv;
        else             vT[((size_t)bh * 64 + d) * 2048 + n] = hv;
      }
    }
}

// ---------------- flash attention v3 ----------------
// 1-D grid of 512 blocks, 8 waves (512 thr). QBLK=256 (wave: 32 rows = 2 frags).
// K/V tiles (64x64) staged once per block in LDS, double-buffered, counted vmcnt.
// Swapped QK^T: lane holds S[q = fq*16 + lr][kv = nt*16 + lg*4 + r], log2 domain.

__global__ __launch_bounds__(512, 4) void attn_fwd(const ushort* __restrict__ q,
                                                   const ushort* __restrict__ k,
                                                   const ushort* __restrict__ vT,
                                                   ushort* __restrict__ o) {
  __shared__ __align__(16) ushort sK[2][64 * 64];
  __shared__ __align__(16) ushort sV[2][64 * 64];
  __shared__ __align__(16) ushort sP[8][2][16 * 64];

  const int tid = threadIdx.x, lane = tid & 63, w = tid >> 6;
  // bijective XCD swizzle: XCD (id&7) owns bh in [xcd*8, xcd*8+8) -> 4MB L2 set
  const int id = blockIdx.x;
  const int xcd = id & 7, j = id >> 3;
  const int bh = xcd * 8 + (j & 7);
  const int qx = j >> 3;
  const int qrow0 = qx * 256 + w * 32;

  const ushort* Qb = q + (size_t)bh * 2048 * 64;
  const ushort* Kb = k + (size_t)bh * 2048 * 64;
  const ushort* Vb = vT + (size_t)bh * 64 * 2048;
  const int lr = lane & 15, lg = lane >> 4;
  const int swz = (lr & 7) << 4;

  // staging geometry: wave w stages rows w*8..w*8+7; lane: row += lane>>3,
  // 16B chunk (lane&7) with inverse XOR-swizzle on the global source (rule #21)
  const int srow = lane >> 3;
  const int ssw = ((lane & 7) ^ srow) * 8;  // element offset in row
  const int krow = w * 8 + srow;

  // prologue: stage tile 0
  gload_lds16(Kb + (size_t)krow * 64 + ssw, &sK[0][w * 512]);
  gload_lds16(Vb + (size_t)krow * 2048 + 0 + ssw, &sV[0][w * 512]);

  // Q fragments, pre-scaled by 0.125 * log2(e) -> scores in log2 domain
  const float qs = 0.125f * 1.44269504f;
  bf16x8 qf[2][2];
  #pragma unroll
  for (int fq = 0; fq < 2; ++fq)
    #pragma unroll
    for (int ks = 0; ks < 2; ++ks) {
      bf16x8 t = *(const bf16x8*)(Qb + (size_t)(qrow0 + fq * 16 + lr) * 64 + ks * 32 + lg * 8);
      #pragma unroll
      for (int jj = 0; jj < 8; ++jj)
        t[jj] = (short)f2bf(bf2f((ushort)t[jj]) * qs);
      qf[fq][ks] = t;
    }

  float m_run[2] = {-1e30f, -1e30f}, l_run[2] = {0.f, 0.f};
  f32x4 oacc[2][4] = {};

  for (int t = 0; t < 32; ++t) {
    const int cur = t & 1;
    if (t + 1 < 32) {
      const int kv2 = (t + 1) << 6;
      gload_lds16(Kb + (size_t)(kv2 + krow) * 64 + ssw, &sK[cur ^ 1][w * 512]);
      gload_lds16(Vb + (size_t)krow * 2048 + kv2 + ssw, &sV[cur ^ 1][w * 512]);
      asm volatile("s_waitcnt vmcnt(2)" ::: "memory");
    } else {
      asm volatile("s_waitcnt vmcnt(0)" ::: "memory");
    }
    __builtin_amdgcn_s_barrier();
    __builtin_amdgcn_sched_barrier(0);

    const char* kb_ = (const char*)&sK[cur][0];
    const char* vb_ = (const char*)&sV[cur][0];

    // QK^T (swapped): s[fq][nt] col=lr -> q row, rows -> kv
    f32x4 s[2][4] = {};
    __builtin_amdgcn_s_setprio(1);
    #pragma unroll
    for (int nt = 0; nt < 4; ++nt) {
      bf16x8 kf0 = *(const bf16x8*)(kb_ + (nt * 16 + lr) * 128 + ((0 * 64 + lg * 16) ^ swz));
      bf16x8 kf1 = *(const bf16x8*)(kb_ + (nt * 16 + lr) * 128 + ((1 * 64 + lg * 16) ^ swz));
      #pragma unroll
      for (int fq = 0; fq < 2; ++fq) {
        s[fq][nt] = __builtin_amdgcn_mfma_f32_16x16x32_bf16(kf0, qf[fq][0], s[fq][nt], 0, 0, 0);
        s[fq][nt] = __builtin_amdgcn_mfma_f32_16x16x32_bf16(kf1, qf[fq][1], s[fq][nt], 0, 0, 0);
      }
    }
    __builtin_amdgcn_s_setprio(0);

    // softmax (log2 domain), defer-max
    float pmax[2];
    #pragma unroll
    for (int fq = 0; fq < 2; ++fq) {
      float mx = s[fq][0][0];
      #pragma unroll
      for (int nt = 0; nt < 4; ++nt)
        #pragma unroll
        for (int r = 0; r < 4; ++r) mx = fmaxf(mx, s[fq][nt][r]);
      pmax[fq] = mx;
    }
    if (!__all((pmax[0] <= m_run[0] + 8.f) && (pmax[1] <= m_run[1] + 8.f))) {
      #pragma unroll
      for (int fq = 0; fq < 2; ++fq) {
        float rm = fmaxf(pmax[fq], __shfl_xor(pmax[fq], 16, 64));
        rm = fmaxf(rm, __shfl_xor(rm, 32, 64));
        const float mnew = fmaxf(m_run[fq], rm);
        const float corr = __builtin_amdgcn_exp2f(m_run[fq] - mnew);
        m_run[fq] = mnew;
        l_run[fq] *= corr;
        #pragma unroll
        for (int r = 0; r < 4; ++r) {
          const float c = __shfl(corr, lg * 4 + r, 64);
          #pragma unroll
          for (int dt = 0; dt < 4; ++dt) oacc[fq][dt][r] *= c;
        }
      }
    }
    #pragma unroll
    for (int fq = 0; fq < 2; ++fq) {
      char* pbf = (char*)&sP[w][fq][0];
      float psum = 0.f;
      #pragma unroll
      for (int nt = 0; nt < 4; ++nt) {
        u16x4 u;
        #pragma unroll
        for (int r = 0; r < 4; ++r) {
          const float e = __builtin_amdgcn_exp2f(s[fq][nt][r] - m_run[fq]);
          psum += e;
          u[r] = f2bf(e);
        }
        *(u16x4*)(pbf + lr * 128 + ((nt * 32 + lg * 8) ^ swz)) = u;
      }
      psum += __shfl_xor(psum, 16, 64);
      psum += __shfl_xor(psum, 32, 64);
      l_run[fq] += psum;
    }

    // PV: A = P rows (q-major), B = V^T rows (d-major) from LDS
    bf16x8 pa[2][2];
    #pragma unroll
    for (int fq = 0; fq < 2; ++fq)
      #pragma unroll
      for (int ks = 0; ks < 2; ++ks)
        pa[fq][ks] = *(const bf16x8*)((const char*)&sP[w][fq][0] + lr * 128 + ((ks * 64 + lg * 16) ^ swz));
    __builtin_amdgcn_s_setprio(1);
    #pragma unroll
    for (int dt = 0; dt < 4; ++dt) {
      bf16x8 vf0 = *(const bf16x8*)(vb_ + (dt * 16 + lr) * 128 + ((0 * 64 + lg * 16) ^ swz));
      bf16x8 vf1 = *(const bf16x8*)(vb_ + (dt * 16 + lr) * 128 + ((1 * 64 + lg * 16) ^ swz));
      #pragma unroll
      for (int fq = 0; fq < 2; ++fq) {
        oacc[fq][dt] = __builtin_amdgcn_mfma_f32_16x16x32_bf16(pa[fq][0], vf0, oacc[fq][dt], 0, 0, 0);
        oacc[fq][dt] = __builtin_amdgcn_mfma_f32_16x16x32_bf16(pa[fq][1], vf1, oacc[fq][dt], 0, 0, 0);
      }
    }
    __builtin_amdgcn_s_setprio(0);
    __builtin_amdgcn_s_barrier();
  }

  // epilogue: O row n = qrow0 + fq*16 + lg*4 + r, col = dt*16 + lr
  const int b_ = bh >> 4, h = bh & 15;
  #pragma unroll
  for (int fq = 0; fq < 2; ++fq) {
    float lf[4];
    #pragma unroll
    for (int r = 0; r < 4; ++r)
      lf[r] = __builtin_amdgcn_rcpf(__shfl(l_run[fq], lg * 4 + r, 64));
    #pragma unroll
    for (int dt = 0; dt < 4; ++dt)
      #pragma unroll
      for (int r = 0; r < 4; ++r) {
        const int n = qrow0 + fq * 16 + lg * 4 + r;
        o[(((size_t)b_ * 2048 + n) * 16 + h) * 64 + dt * 16 + lr] = f2bf(oacc[fq][dt][r] * lf[r]);
      }
  }
}

// ---------------- GEMM2: out = attn @ w_out + b_out (f32 out) ----------------

__global__ void gemm_out(const ushort* __restrict__ A, const ushort* __restrict__ Bt,
                         const float* __restrict__ bias, float* __restrict__ out) {
  constexpr int K = 1024;
  __shared__ __align__(16) ushort sA[128 * 32];
  __shared__ __align__(16) ushort sB[128 * 32];
  const int tid = threadIdx.x;
  const int lane = tid & 63;
  const int w = tid >> 6;
  const int wr = w >> 1, wc = w & 1;
  const int bm = blockIdx.y * 128;
  const int bn = blockIdx.x * 128;
  f32x4 acc[4][4] = {};
  const int srow = lane >> 2;
  const int skb = (lane & 3) * 8;

  for (int kt = 0; kt < K; kt += 32) {
    #pragma unroll
    for (int i = 0; i < 2; ++i) {
      const int chunk = w * 2 + i;
      const int row = chunk * 16 + srow;
      gload_lds16(A + (size_t)(bm + row) * K + kt + skb, sA + chunk * 512);
      gload_lds16(Bt + (size_t)(bn + row) * K + kt + skb, sB + chunk * 512);
    }
    __syncthreads();
    bf16x8 af[4], bfr[4];
    #pragma unroll
    for (int mi = 0; mi < 4; ++mi)
      af[mi] = *(const bf16x8*)(sA + (wr * 64 + mi * 16 + (lane & 15)) * 32 + (lane >> 4) * 8);
    #pragma unroll
    for (int ni = 0; ni < 4; ++ni)
      bfr[ni] = *(const bf16x8*)(sB + (wc * 64 + ni * 16 + (lane & 15)) * 32 + (lane >> 4) * 8);
    #pragma unroll
    for (int mi = 0; mi < 4; ++mi)
      #pragma unroll
      for (int ni = 0; ni < 4; ++ni)
        acc[mi][ni] = __builtin_amdgcn_mfma_f32_16x16x32_bf16(af[mi], bfr[ni], acc[mi][ni], 0, 0, 0);
    __syncthreads();
  }

  #pragma unroll
  for (int mi = 0; mi < 4; ++mi)
    #pragma unroll
    for (int ni = 0; ni < 4; ++ni) {
      const int col = bn + wc * 64 + ni * 16 + (lane & 15);
      const float bb = bias[col];
      #pragma unroll
      for (int r = 0; r < 4; ++r) {
        const int row = bm + wr * 64 + mi * 16 + (lane >> 4) * 4 + r;
        out[(size_t)row * 1024 + col] = acc[mi][ni][r] + bb;
      }
    }
}

// ---------------- launch ----------------

extern "C" void kernel_launch(void* const* d_in, const int* in_sizes, int n_in,
                              void* d_out, int out_size, void* d_ws, size_t ws_size,
                              hipStream_t stream) {
  const float* x = (const float*)d_in[0];
  const float* w_qkv = (const float*)d_in[1];
  const float* b_qkv = (const float*)d_in[2];
  const float* w_out = (const float*)d_in[3];
  const float* b_out = (const float*)d_in[4];
  float* out = (float*)d_out;
  char* ws = (char*)d_ws;

  ushort* xb    = (ushort*)(ws);                 // 16 MiB
  ushort* wqkvT = (ushort*)(ws + 16777216);      // 6 MiB
  ushort* woutT = (ushort*)(ws + 23068672);      // 2 MiB
  ushort* qb    = (ushort*)(ws + 25165824);      // 16 MiB
  ushort* kb    = (ushort*)(ws + 41943040);      // 16 MiB
  ushort* vTb   = (ushort*)(ws + 58720256);      // 16 MiB
  ushort* attnb = (ushort*)(ws + 75497472);      // 16 MiB

  cvt_f32_bf16<<<2048, 256, 0, stream>>>(x, xb, 8192 * 1024);
  transpose_cvt<<<dim3(96, 32), dim3(32, 8), 0, stream>>>(w_qkv, wqkvT, 1024, 3072);
  transpose_cvt<<<dim3(32, 32), dim3(32, 8), 0, stream>>>(w_out, woutT, 1024, 1024);
  gemm_qkv<<<dim3(24, 64), 256, 0, stream>>>(xb, wqkvT, b_qkv, qb, kb, vTb);
  attn_fwd<<<512, 512, 0, stream>>>(qb, kb, vTb, attnb);
  gemm_out<<<dim3(8, 64), 256, 0, stream>>>(attnb, woutT, b_out, out);
}

// Round 4
// 217.262 us; speedup vs baseline: 2.6967x; 1.1475x over previous
//
#include <hip/hip_runtime.h>

typedef __attribute__((ext_vector_type(8))) short bf16x8;
typedef __attribute__((ext_vector_type(4))) float f32x4;
typedef __attribute__((ext_vector_type(16))) float f32x16;
typedef __attribute__((ext_vector_type(4))) ushort u16x4;

__device__ __forceinline__ ushort f2bf(float f) {
  union { float f; unsigned u; } v; v.f = f;
  unsigned r = v.u + 0x7fffu + ((v.u >> 16) & 1u);
  return (ushort)(r >> 16);
}

__device__ __forceinline__ float bf2f(ushort u) {
  union { float f; unsigned u; } v; v.u = (unsigned)u << 16;
  return v.f;
}

__device__ __forceinline__ unsigned cvt_pk_bf16(float lo, float hi) {
  unsigned r;
  asm("v_cvt_pk_bf16_f32 %0, %1, %2" : "=v"(r) : "v"(lo), "v"(hi));
  return r;
}

// vdst' = [vdst.lo | vsrc.lo], vsrc' = [vdst.hi | vsrc.hi]
__device__ __forceinline__ void permlane32_swap(unsigned& x, unsigned& y) {
  asm("v_permlane32_swap_b32 %0, %1" : "+v"(x), "+v"(y));
}

__device__ __forceinline__ void gload_lds16(const void* g, void* l) {
  __builtin_amdgcn_global_load_lds(
      (const __attribute__((address_space(1))) void*)g,
      (__attribute__((address_space(3))) void*)l, 16, 0, 0);
}

// ---------------- conversion kernels ----------------

__global__ void cvt_f32_bf16(const float* __restrict__ s, ushort* __restrict__ d, int n) {
  int i = (blockIdx.x * blockDim.x + threadIdx.x) * 4;
  int stride = gridDim.x * blockDim.x * 4;
  for (; i < n; i += stride) {
    float4 v = *reinterpret_cast<const float4*>(s + i);
    ushort4 o;
    o.x = f2bf(v.x); o.y = f2bf(v.y); o.z = f2bf(v.z); o.w = f2bf(v.w);
    *reinterpret_cast<ushort4*>(d + i) = o;
  }
}

// src [R][C] f32 -> dst [C][R] bf16
__global__ void transpose_cvt(const float* __restrict__ src, ushort* __restrict__ dst,
                              int R, int C) {
  __shared__ float tile[32][33];
  int c0 = blockIdx.x * 32, r0 = blockIdx.y * 32;
  int tx = threadIdx.x, ty = threadIdx.y;  // 32 x 8
  #pragma unroll
  for (int i = 0; i < 32; i += 8)
    tile[ty + i][tx] = src[(size_t)(r0 + ty + i) * C + c0 + tx];
  __syncthreads();
  #pragma unroll
  for (int i = 0; i < 32; i += 8)
    dst[(size_t)(c0 + ty + i) * R + r0 + tx] = f2bf(tile[tx][ty + i]);
}

// ---------------- GEMM1: qkv = x @ w_qkv + b, scatter to q/k/vT ----------------

__global__ void gemm_qkv(const ushort* __restrict__ A, const ushort* __restrict__ Bt,
                         const float* __restrict__ bias,
                         ushort* __restrict__ q, ushort* __restrict__ k,
                         ushort* __restrict__ vT) {
  constexpr int K = 1024;
  __shared__ __align__(16) ushort sA[128 * 32];
  __shared__ __align__(16) ushort sB[128 * 32];
  const int tid = threadIdx.x;
  const int lane = tid & 63;
  const int w = tid >> 6;
  const int wr = w >> 1, wc = w & 1;
  const int bm = blockIdx.y * 128;
  const int bn = blockIdx.x * 128;
  f32x4 acc[4][4] = {};
  const int srow = lane >> 2;
  const int skb = (lane & 3) * 8;

  for (int kt = 0; kt < K; kt += 32) {
    #pragma unroll
    for (int i = 0; i < 2; ++i) {
      const int chunk = w * 2 + i;
      const int row = chunk * 16 + srow;
      gload_lds16(A + (size_t)(bm + row) * K + kt + skb, sA + chunk * 512);
      gload_lds16(Bt + (size_t)(bn + row) * K + kt + skb, sB + chunk * 512);
    }
    __syncthreads();
    bf16x8 af[4], bfr[4];
    #pragma unroll
    for (int mi = 0; mi < 4; ++mi)
      af[mi] = *(const bf16x8*)(sA + (wr * 64 + mi * 16 + (lane & 15)) * 32 + (lane >> 4) * 8);
    #pragma unroll
    for (int ni = 0; ni < 4; ++ni)
      bfr[ni] = *(const bf16x8*)(sB + (wc * 64 + ni * 16 + (lane & 15)) * 32 + (lane >> 4) * 8);
    #pragma unroll
    for (int mi = 0; mi < 4; ++mi)
      #pragma unroll
      for (int ni = 0; ni < 4; ++ni)
        acc[mi][ni] = __builtin_amdgcn_mfma_f32_16x16x32_bf16(af[mi], bfr[ni], acc[mi][ni], 0, 0, 0);
    __syncthreads();
  }

  #pragma unroll
  for (int mi = 0; mi < 4; ++mi)
    #pragma unroll
    for (int ni = 0; ni < 4; ++ni) {
      const int col = bn + wc * 64 + ni * 16 + (lane & 15);
      const int t = col >> 10;
      const int h = (col >> 6) & 15;
      const int d = col & 63;
      const float bb = bias[col];
      #pragma unroll
      for (int r = 0; r < 4; ++r) {
        const int row = bm + wr * 64 + mi * 16 + (lane >> 4) * 4 + r;
        const int b_ = row >> 11, n = row & 2047;
        const int bh = b_ * 16 + h;
        const ushort hv = f2bf(acc[mi][ni][r] + bb);
        if (t == 0)      q[((size_t)bh * 2048 + n) * 64 + d] = hv;
        else if (t == 1) k[((size_t)bh * 2048 + n) * 64 + d] = hv;
        else             vT[((size_t)bh * 64 + d) * 2048 + n] = hv;
      }
    }
}

// ---------------- flash attention v4: 32x32 MFMA, in-register P ----------------
// grid 512, 8 waves (512 thr). Wave owns 32 q-rows -> QBLK=256. KVBLK=64.
// Swapped QK^T (32x32x16): lane holds S[q = lane&31][kv = (r&3)+8*(r>>2)+4*(lane>>5)]
// for kvt*32 tile. P rebuilt in-register via cvt_pk + permlane32_swap (T12).

__global__ __launch_bounds__(512, 2) void attn_fwd(const ushort* __restrict__ q,
                                                   const ushort* __restrict__ k,
                                                   const ushort* __restrict__ vT,
                                                   ushort* __restrict__ o) {
  __shared__ __align__(16) ushort sK[2][64 * 64];
  __shared__ __align__(16) ushort sV[2][64 * 64];

  const int tid = threadIdx.x, lane = tid & 63, w = tid >> 6;
  const int id = blockIdx.x;
  const int xcd = id & 7, j = id >> 3;
  const int bh = xcd * 8 + (j & 7);
  const int qx = j >> 3;
  const int qrow0 = qx * 256 + w * 32;

  const ushort* Qb = q + (size_t)bh * 2048 * 64;
  const ushort* Kb = k + (size_t)bh * 2048 * 64;
  const ushort* Vb = vT + (size_t)bh * 64 * 2048;
  const int lq = lane & 31, hi = lane >> 5;

  // staging: wave w stages rows w*8..w*8+7; inverse XOR-swizzled source (rule #21)
  const int srow = lane >> 3;
  const int ssw = ((lane & 7) ^ srow) * 8;
  const int krow = w * 8 + srow;

  gload_lds16(Kb + (size_t)krow * 64 + ssw, &sK[0][w * 512]);
  gload_lds16(Vb + (size_t)krow * 2048 + 0 + ssw, &sV[0][w * 512]);

  // Q fragments (B-operand): lane needs Q[q=lq][d = dk*16 + hi*8 + j], scaled
  const float qs = 0.125f * 1.44269504f;  // 1/sqrt(64) * log2(e)
  bf16x8 qf[4];
  #pragma unroll
  for (int dk = 0; dk < 4; ++dk) {
    bf16x8 t = *(const bf16x8*)(Qb + (size_t)(qrow0 + lq) * 64 + dk * 16 + hi * 8);
    #pragma unroll
    for (int jj = 0; jj < 8; ++jj)
      t[jj] = (short)f2bf(bf2f((ushort)t[jj]) * qs);
    qf[dk] = t;
  }

  float m_run = -1e30f, l_run = 0.f;
  f32x16 oacc[2] = {};

  for (int t = 0; t < 32; ++t) {
    const int cur = t & 1;
    if (t + 1 < 32) {
      const int kv2 = (t + 1) << 6;
      gload_lds16(Kb + (size_t)(kv2 + krow) * 64 + ssw, &sK[cur ^ 1][w * 512]);
      gload_lds16(Vb + (size_t)krow * 2048 + kv2 + ssw, &sV[cur ^ 1][w * 512]);
      asm volatile("s_waitcnt vmcnt(2)" ::: "memory");
    } else {
      asm volatile("s_waitcnt vmcnt(0)" ::: "memory");
    }
    __builtin_amdgcn_s_barrier();
    __builtin_amdgcn_sched_barrier(0);

    const char* kb_ = (const char*)&sK[cur][0];
    const char* vb_ = (const char*)&sV[cur][0];

    // QK^T swapped: S[kvt] = K_tile x Q^T; lane q = lq
    f32x16 S[2] = {};
    __builtin_amdgcn_s_setprio(1);
    #pragma unroll
    for (int kvt = 0; kvt < 2; ++kvt) {
      const int row = kvt * 32 + lq;
      const int rsw = (row & 7) << 4;
      #pragma unroll
      for (int dk = 0; dk < 4; ++dk) {
        bf16x8 kf = *(const bf16x8*)(kb_ + row * 128 + ((dk * 32 + hi * 16) ^ rsw));
        S[kvt] = __builtin_amdgcn_mfma_f32_32x32x16_bf16(kf, qf[dk], S[kvt], 0, 0, 0);
      }
    }
    __builtin_amdgcn_s_setprio(0);

    // in-lane row max over 32 S values (+1 shfl across halves)
    float mx = S[0][0];
    #pragma unroll
    for (int kvt = 0; kvt < 2; ++kvt)
      #pragma unroll
      for (int r = 0; r < 16; ++r) mx = fmaxf(mx, S[kvt][r]);
    const float rm = fmaxf(mx, __shfl_xor(mx, 32, 64));

    // defer-max (T13, log2 domain, thr 8 -> P <= 256, fine in bf16)
    if (!__all(rm <= m_run + 8.f)) {
      const float mnew = fmaxf(m_run, rm);
      const float corr = __builtin_amdgcn_exp2f(m_run - mnew);
      m_run = mnew;
      l_run *= corr;
      float cq[16];
      #pragma unroll
      for (int r = 0; r < 16; ++r)
        cq[r] = __shfl(corr, (r & 3) + 8 * (r >> 2) + 4 * hi, 64);
      #pragma unroll
      for (int dt = 0; dt < 2; ++dt)
        #pragma unroll
        for (int r = 0; r < 16; ++r) oacc[dt][r] *= cq[r];
    }

    // exp2 + pack P to bf16 dword pairs (in-register)
    float psum = 0.f;
    unsigned pk_[2][8];
    #pragma unroll
    for (int kvt = 0; kvt < 2; ++kvt) {
      float e[16];
      #pragma unroll
      for (int r = 0; r < 16; ++r) {
        e[r] = __builtin_amdgcn_exp2f(S[kvt][r] - m_run);
        psum += e[r];
      }
      #pragma unroll
      for (int g = 0; g < 4; ++g) {
        pk_[kvt][g * 2 + 0] = cvt_pk_bf16(e[4 * g + 0], e[4 * g + 1]);
        pk_[kvt][g * 2 + 1] = cvt_pk_bf16(e[4 * g + 2], e[4 * g + 3]);
      }
    }
    psum += __shfl_xor(psum, 32, 64);
    l_run += psum;

    // PV: A = P fragment via permlane32_swap; B = V from LDS
    __builtin_amdgcn_s_setprio(1);
    #pragma unroll
    for (int kvt = 0; kvt < 2; ++kvt)
      #pragma unroll
      for (int cc = 0; cc < 2; ++cc) {
        unsigned x0 = pk_[kvt][4 * cc + 0], x1 = pk_[kvt][4 * cc + 1];
        unsigned y0 = pk_[kvt][4 * cc + 2], y1 = pk_[kvt][4 * cc + 3];
        permlane32_swap(x0, y0);
        permlane32_swap(x1, y1);
        union { unsigned u[4]; bf16x8 v; } A;
        A.u[0] = x0; A.u[1] = x1; A.u[2] = y0; A.u[3] = y1;
        const int cg = kvt * 2 + cc;
        #pragma unroll
        for (int dt = 0; dt < 2; ++dt) {
          const int row = dt * 32 + lq;
          bf16x8 vf = *(const bf16x8*)(vb_ + row * 128 + ((cg * 32 + hi * 16) ^ ((row & 7) << 4)));
          oacc[dt] = __builtin_amdgcn_mfma_f32_32x32x16_bf16(A.v, vf, oacc[dt], 0, 0, 0);
        }
      }
    __builtin_amdgcn_s_setprio(0);
    __builtin_amdgcn_s_barrier();
  }

  // epilogue: oacc row q' = (r&3)+8*(r>>2)+4*hi, col d = dt*32+lq
  const int b_ = bh >> 4, h = bh & 15;
  float lf[16];
  #pragma unroll
  for (int r = 0; r < 16; ++r)
    lf[r] = __builtin_amdgcn_rcpf(__shfl(l_run, (r & 3) + 8 * (r >> 2) + 4 * hi, 64));
  #pragma unroll
  for (int dt = 0; dt < 2; ++dt)
    #pragma unroll
    for (int r = 0; r < 16; ++r) {
      const int n = qrow0 + (r & 3) + 8 * (r >> 2) + 4 * hi;
      o[(((size_t)b_ * 2048 + n) * 16 + h) * 64 + dt * 32 + lq] = f2bf(oacc[dt][r] * lf[r]);
    }
}

// ---------------- GEMM2: out = attn @ w_out + b_out (f32 out) ----------------

__global__ void gemm_out(const ushort* __restrict__ A, const ushort* __restrict__ Bt,
                         const float* __restrict__ bias, float* __restrict__ out) {
  constexpr int K = 1024;
  __shared__ __align__(16) ushort sA[128 * 32];
  __shared__ __align__(16) ushort sB[128 * 32];
  const int tid = threadIdx.x;
  const int lane = tid & 63;
  const int w = tid >> 6;
  const int wr = w >> 1, wc = w & 1;
  const int bm = blockIdx.y * 128;
  const int bn = blockIdx.x * 128;
  f32x4 acc[4][4] = {};
  const int srow = lane >> 2;
  const int skb = (lane & 3) * 8;

  for (int kt = 0; kt < K; kt += 32) {
    #pragma unroll
    for (int i = 0; i < 2; ++i) {
      const int chunk = w * 2 + i;
      const int row = chunk * 16 + srow;
      gload_lds16(A + (size_t)(bm + row) * K + kt + skb, sA + chunk * 512);
      gload_lds16(Bt + (size_t)(bn + row) * K + kt + skb, sB + chunk * 512);
    }
    __syncthreads();
    bf16x8 af[4], bfr[4];
    #pragma unroll
    for (int mi = 0; mi < 4; ++mi)
      af[mi] = *(const bf16x8*)(sA + (wr * 64 + mi * 16 + (lane & 15)) * 32 + (lane >> 4) * 8);
    #pragma unroll
    for (int ni = 0; ni < 4; ++ni)
      bfr[ni] = *(const bf16x8*)(sB + (wc * 64 + ni * 16 + (lane & 15)) * 32 + (lane >> 4) * 8);
    #pragma unroll
    for (int mi = 0; mi < 4; ++mi)
      #pragma unroll
      for (int ni = 0; ni < 4; ++ni)
        acc[mi][ni] = __builtin_amdgcn_mfma_f32_16x16x32_bf16(af[mi], bfr[ni], acc[mi][ni], 0, 0, 0);
    __syncthreads();
  }

  #pragma unroll
  for (int mi = 0; mi < 4; ++mi)
    #pragma unroll
    for (int ni = 0; ni < 4; ++ni) {
      const int col = bn + wc * 64 + ni * 16 + (lane & 15);
      const float bb = bias[col];
      #pragma unroll
      for (int r = 0; r < 4; ++r) {
        const int row = bm + wr * 64 + mi * 16 + (lane >> 4) * 4 + r;
        out[(size_t)row * 1024 + col] = acc[mi][ni][r] + bb;
      }
    }
}

// ---------------- launch ----------------

extern "C" void kernel_launch(void* const* d_in, const int* in_sizes, int n_in,
                              void* d_out, int out_size, void* d_ws, size_t ws_size,
                              hipStream_t stream) {
  const float* x = (const float*)d_in[0];
  const float* w_qkv = (const float*)d_in[1];
  const float* b_qkv = (const float*)d_in[2];
  const float* w_out = (const float*)d_in[3];
  const float* b_out = (const float*)d_in[4];
  float* out = (float*)d_out;
  char* ws = (char*)d_ws;

  ushort* xb    = (ushort*)(ws);                 // 16 MiB
  ushort* wqkvT = (ushort*)(ws + 16777216);      // 6 MiB
  ushort* woutT = (ushort*)(ws + 23068672);      // 2 MiB
  ushort* qb    = (ushort*)(ws + 25165824);      // 16 MiB
  ushort* kb    = (ushort*)(ws + 41943040);      // 16 MiB
  ushort* vTb   = (ushort*)(ws + 58720256);      // 16 MiB
  ushort* attnb = (ushort*)(ws + 75497472);      // 16 MiB

  cvt_f32_bf16<<<2048, 256, 0, stream>>>(x, xb, 8192 * 1024);
  transpose_cvt<<<dim3(96, 32), dim3(32, 8), 0, stream>>>(w_qkv, wqkvT, 1024, 3072);
  transpose_cvt<<<dim3(32, 32), dim3(32, 8), 0, stream>>>(w_out, woutT, 1024, 1024);
  gemm_qkv<<<dim3(24, 64), 256, 0, stream>>>(xb, wqkvT, b_qkv, qb, kb, vTb);
  attn_fwd<<<512, 512, 0, stream>>>(qb, kb, vTb, attnb);
  gemm_out<<<dim3(8, 64), 256, 0, stream>>>(attnb, woutT, b_out, out);
}